// Round 1
// baseline (21.722 us; speedup 1.0000x reference)
//
#include <hip/hip_runtime.h>
#include <math.h>

#define HW 128
#define EPSF 1e-4f
#define L2E 1.4426950408889634f
#define NPART 16            // partial images
#define WPB 8               // waves per accum block
#define NP 8                // pixel rows per lane
#define NTILE (HW / NP)     // 16 row-band tiles
#define NGROUPS (NPART * WPB)   // 128 splat groups
#define NUNI 5              // per-splat uniforms: u1, col0..3 (2^-96-scaled)
#define DLT (1.0f / HW)
#define SHIFTF 96.0f        // exponent pre-bias folded into qc (colors scaled 2^-96)
#define CSCALE 0x1p-96f
#define DCLAMP 18.0f        // per-row log2-step clamp (R <= 2^18, no overflow)

typedef float f2 __attribute__((ext_vector_type(2)));

__device__ __forceinline__ float ex2(float x) {        // 2^x
    float r; asm("v_exp_f32 %0, %1" : "=v"(r) : "v"(x)); return r;
}
__device__ __forceinline__ float rcp_(float x) {       // 1/x
    float r; asm("v_rcp_f32 %0, %1" : "=v"(r) : "v"(x)); return r;
}
__device__ __forceinline__ float fsig(float x) {       // sigmoid
    return rcp_(1.0f + ex2(-L2E * x));
}
__device__ __forceinline__ float ftanh(float x) {      // tanh = 1 - 2/(e^2x+1)
    return 1.0f - 2.0f * rcp_(1.0f + ex2((2.0f * L2E) * x));
}

// One WAVE per splat (4 splats / 256-thr block). Computes polynomial coeffs
// of z*log2e = u0 x^2 + u1 y^2 + u2 xy + u3 x + u4 y + u5 (logdet/log2pi
// cancel in exp(k - k.max())), grid max m via per-column y-vertex, stores
//   tab[n][lane] = (qb_lo, qc_lo - m + 96, qb_hi, qc_hi - m + 96)
//   qb = u2 x + u4,  qc = (u0 x + u3)x + u5,  cols lo=lane, hi=64+lane
// and 5 per-splat uniforms SoA-blocked per splat-group for accum s_load:
//   urec[g*spw*5 + {0..4}*spw + o] = {u1, c0*2^-96, c1*2^-96, c2*2^-96, c3*2^-96}
// The +96 bias / 2^-96 color scale keep the accum row-recurrence's W~ in
// normal-f32 range (W~ <= 2^96 since z - m <= 0; products are bit-identical
// to the unbiased ones). Pad splats (n >= n_splats): qc' = -16384 -> W = 0.
__global__ __launch_bounds__(256) void splat_setup_max(
    const float* __restrict__ rho, const float* __restrict__ sigma,
    const float* __restrict__ coords, const float* __restrict__ alpha,
    const float* __restrict__ colors, const float* __restrict__ tm,
    float4* __restrict__ tab, float* __restrict__ urec,
    int n_splats, int nsp_pad)
{
    const int lane = threadIdx.x & 63;
    const int n = blockIdx.x * 4 + (threadIdx.x >> 6);
    if (n >= nsp_pad) return;

    const int spw = nsp_pad >> 7;              // nsp_pad / NGROUPS
    const int g   = n / spw;
    const int o   = n - g * spw;
    float* ub = urec + (size_t)g * spw * NUNI;

    if (n >= n_splats) {                       // zero-contribution pad record
        tab[(size_t)n * 64 + lane] = make_float4(0.0f, -16384.0f, 0.0f, -16384.0f);
        if (lane == 0) {
#pragma unroll
            for (int i = 0; i < NUNI; ++i) ub[i * spw + o] = 0.0f;
        }
        return;
    }

    float T[16];
#pragma unroll
    for (int i = 0; i < 16; ++i) T[i] = tm[i];

    const float a  = fsig(alpha[n]);
    const float r  = fsig(rho[n]) + EPSF;
    const float s0 = fsig(-sigma[n * 3 + 0]);
    const float s1 = fsig(-sigma[n * 3 + 1]);
    const float s2 = fsig(-sigma[n * 3 + 2]);
    const float sx = T[0] * s0 + T[1] * s1 + T[2]  * s2 + T[3];
    const float sy = T[4] * s0 + T[5] * s1 + T[6]  * s2 + T[7];
    const float sz = T[8] * s0 + T[9] * s1 + T[10] * s2 + T[11];

    const float c0 = ftanh(coords[n * 3 + 0]) + 0.5f;
    const float c1 = ftanh(coords[n * 3 + 1]) + 0.5f;
    const float c2 = ftanh(coords[n * 3 + 2]) + 0.5f;
    const float cx = T[0] * c0 + T[1] * c1 + T[2]  * c2 + T[3];
    const float cy = T[4] * c0 + T[5] * c1 + T[6]  * c2 + T[7];
    const float cz = T[8] * c0 + T[9] * c1 + T[10] * c2 + T[11];

    const float col0 = ftanh(colors[n * 4 + 0] * a);
    const float col1 = ftanh(colors[n * 4 + 1] * a);
    const float col2 = ftanh(colors[n * 4 + 2] * a);
    const float col3 = ftanh(colors[n * 4 + 3] * a);

    const float M00 = sx * sx + EPSF, M01 = sx * sy * r, M02 = sx * sz * r;
    const float M11 = sy * sy + EPSF, M12 = sy * sz * r, M22 = sz * sz + EPSF;

    const float C00 = M11 * M22 - M12 * M12;
    const float C01 = M02 * M12 - M01 * M22;
    const float C02 = M01 * M12 - M02 * M11;
    const float det = M00 * C00 + M01 * C01 + M02 * C02;
    const float idet = -0.5f / det;
    const float A00 = C00 * idet;
    const float A01 = C01 * idet;
    const float A02 = C02 * idet;
    const float A11 = (M00 * M22 - M02 * M02) * idet;
    const float A12 = (M01 * M02 - M00 * M12) * idet;
    const float A22 = (M00 * M11 - M01 * M01) * idet;

    const float pz = cz + 1.0f;
    const float u0 = A00 * L2E;
    const float u1 = A11 * L2E;
    const float u2 = 2.0f * A01 * L2E;
    const float u3 = 2.0f * (A00 * cx + A01 * cy + A02 * pz) * L2E;
    const float u4 = 2.0f * (A01 * cx + A11 * cy + A12 * pz) * L2E;
    const float u5 = (A00 * cx * cx + A11 * cy * cy + A22 * pz * pz
                      + 2.0f * (A01 * cx * cy + A02 * cx * pz + A12 * cy * pz)) * L2E;

    float qbv[2], qcv[2];
    float m = -INFINITY;
#pragma unroll
    for (int cc = 0; cc < 2; ++cc) {
        const int colx = lane + 64 * cc;
        const float x  = (float)colx * (1.0f / HW);
        const float qb = fmaf(u2, x, u4);
        const float qc = fmaf(fmaf(u0, x, u3), x, u5);
        qbv[cc] = qb; qcv[cc] = qc;
        const float yv = -qb * 0.5f * rcp_(u1);
        int iy = (int)rintf(yv * (float)HW);
        iy = max(1, min(HW - 2, iy));
        const int cand[5] = {0, HW - 1, iy - 1, iy, iy + 1};
#pragma unroll
        for (int q = 0; q < 5; ++q) {
            const float y = (float)cand[q] * (1.0f / HW);
            m = fmaxf(m, fmaf(fmaf(u1, y, qb), y, qc));
        }
    }
#pragma unroll
    for (int off = 32; off > 0; off >>= 1)
        m = fmaxf(m, __shfl_xor(m, off, 64));

    tab[(size_t)n * 64 + lane] =
        make_float4(qbv[0], qcv[0] - m + SHIFTF, qbv[1], qcv[1] - m + SHIFTF);
    if (lane == 0) {
        ub[0 * spw + o] = u1;
        ub[1 * spw + o] = col0 * CSCALE;
        ub[2 * spw + o] = col1 * CSCALE;
        ub[3 * spw + o] = col2 * CSCALE;
        ub[4 * spw + o] = col3 * CSCALE;
    }
}

// 256 blocks (16 row-band tiles x 16 partial-groups) x 512 thr (8 waves).
// Each lane owns TWO columns (lane, 64+lane) x NP=8 rows. Per splat, the
// quadratic-in-y exponent has constant 2nd difference c = 2*u1*DLT^2, so
//   W_{k+1} = W_k * R_k,  R_{k+1} = R_k * s,  s = exp2(c)
// replaces per-pixel exp: 5 v_exp per splat-lane (16 px) instead of 16.
// All math packed f2 across the two columns (v_pk_fma_f32/v_pk_mul_f32,
// SGPR/broadcast operands free in VOP3P). Guards: qc pre-biased +96 with
// colors scaled 2^-96 (keeps rising-from-deep columns in normal range),
// and d clamped <= 18 so R can't overflow; clamp only under-estimates so
// W~ <= true W~ <= 2^96 (residual error <= ~2^-17). Tail: 3-round LDS
// tree, partial store; combine sums NPART partials.
__global__ __launch_bounds__(512, 2) void splat_accum(
    const float4* __restrict__ tab, const float* __restrict__ urec,
    float4* __restrict__ part, int nsp_pad)
{
    __shared__ float4 lred[4][NP][2][64];     // 64 KB

    const int t    = threadIdx.x;
    const int lane = t & 63;
    const int w    = __builtin_amdgcn_readfirstlane(t >> 6);   // wave 0..7
    const int tile = blockIdx.x >> 4;         // row band 0..15
    const int pg   = blockIdx.x & (NPART - 1);
    const int g    = pg * WPB + w;            // splat group 0..127 (scalar)

    const float y0   = (float)(tile * NP) * DLT;
    const float y0sq = y0 * y0;
    const float k0   = DLT * (2.0f * y0 + DLT);   // d0 = qb*DLT + u1*k0
    const float cdl  = 2.0f * DLT * DLT;          // c/u1

    const int spw = nsp_pad >> 7;             // 16 for N=2048
    const int j0  = g * spw;

    f2 acc[4][NP];                            // [channel][row], f2 = {col_lo, col_hi}
#pragma unroll
    for (int c = 0; c < 4; ++c)
#pragma unroll
        for (int r = 0; r < NP; ++r) acc[c][r] = (f2){0.0f, 0.0f};

    const float4* tq = tab + (size_t)j0 * 64 + lane;
    const float*  gb = urec + (size_t)g * spw * NUNI;   // uniform (scalar) ptr

    if (spw == 16) {
        float su1[16], sc0[16], sc1[16], sc2[16], sc3[16];
#pragma unroll
        for (int j = 0; j < 16; ++j) {
            su1[j] = gb[j];
            sc0[j] = gb[16 + j];
            sc1[j] = gb[32 + j];
            sc2[j] = gb[48 + j];
            sc3[j] = gb[64 + j];
        }
#pragma unroll
        for (int j = 0; j < 16; ++j) {
            const float4 q4 = tq[(size_t)j * 64];       // (qb_lo,qc_lo,qb_hi,qc_hi)
            const f2 Qb = (f2){q4.x, q4.z};
            const f2 Qc = (f2){q4.y, q4.w};
            const float sj = ex2(su1[j] * cdl);         // row-ratio step
            f2 Z = Qb * y0 + (Qc + su1[j] * y0sq);      // z at band row 0
            f2 D = Qb * DLT + su1[j] * k0;              // first fwd difference
            D.x = fminf(D.x, DCLAMP);
            D.y = fminf(D.y, DCLAMP);
            f2 W = (f2){ex2(Z.x), ex2(Z.y)};
            f2 R = (f2){ex2(D.x), ex2(D.y)};
#pragma unroll
            for (int r = 0; r < NP; ++r) {
                acc[0][r] = W * sc0[j] + acc[0][r];     // pk_fma, SGPR bcast
                acc[1][r] = W * sc1[j] + acc[1][r];
                acc[2][r] = W * sc2[j] + acc[2][r];
                acc[3][r] = W * sc3[j] + acc[3][r];
                if (r < NP - 1) { W = W * R; R = R * sj; }
            }
        }
    } else {
        for (int j = 0; j < spw; ++j) {
            const float4 q4 = tq[(size_t)j * 64];
            const f2 Qb = (f2){q4.x, q4.z};
            const f2 Qc = (f2){q4.y, q4.w};
            const float u1j = gb[j];
            const float c0j = gb[spw + j];
            const float c1j = gb[2 * spw + j];
            const float c2j = gb[3 * spw + j];
            const float c3j = gb[4 * spw + j];
            const float sj = ex2(u1j * cdl);
            f2 Z = Qb * y0 + (Qc + u1j * y0sq);
            f2 D = Qb * DLT + u1j * k0;
            D.x = fminf(D.x, DCLAMP);
            D.y = fminf(D.y, DCLAMP);
            f2 W = (f2){ex2(Z.x), ex2(Z.y)};
            f2 R = (f2){ex2(D.x), ex2(D.y)};
#pragma unroll
            for (int r = 0; r < NP; ++r) {
                acc[0][r] = W * c0j + acc[0][r];
                acc[1][r] = W * c1j + acc[1][r];
                acc[2][r] = W * c2j + acc[2][r];
                acc[3][r] = W * c3j + acc[3][r];
                if (r < NP - 1) { W = W * R; R = R * sj; }
            }
        }
    }

    // 3-round tree: 8 waves -> 1 (both column halves per round)
    if (w >= 4) {
#pragma unroll
        for (int p = 0; p < NP; ++p) {
            lred[w - 4][p][0][lane] = make_float4(acc[0][p].x, acc[1][p].x, acc[2][p].x, acc[3][p].x);
            lred[w - 4][p][1][lane] = make_float4(acc[0][p].y, acc[1][p].y, acc[2][p].y, acc[3][p].y);
        }
    }
    __syncthreads();
    if (w < 4) {
#pragma unroll
        for (int p = 0; p < NP; ++p) {
            const float4 a = lred[w][p][0][lane];
            const float4 b = lred[w][p][1][lane];
            acc[0][p] += (f2){a.x, b.x};
            acc[1][p] += (f2){a.y, b.y};
            acc[2][p] += (f2){a.z, b.z};
            acc[3][p] += (f2){a.w, b.w};
        }
    }
    __syncthreads();
    if (w == 2 || w == 3) {
#pragma unroll
        for (int p = 0; p < NP; ++p) {
            lred[w - 2][p][0][lane] = make_float4(acc[0][p].x, acc[1][p].x, acc[2][p].x, acc[3][p].x);
            lred[w - 2][p][1][lane] = make_float4(acc[0][p].y, acc[1][p].y, acc[2][p].y, acc[3][p].y);
        }
    }
    __syncthreads();
    if (w < 2) {
#pragma unroll
        for (int p = 0; p < NP; ++p) {
            const float4 a = lred[w][p][0][lane];
            const float4 b = lred[w][p][1][lane];
            acc[0][p] += (f2){a.x, b.x};
            acc[1][p] += (f2){a.y, b.y};
            acc[2][p] += (f2){a.z, b.z};
            acc[3][p] += (f2){a.w, b.w};
        }
    }
    __syncthreads();
    if (w == 1) {
#pragma unroll
        for (int p = 0; p < NP; ++p) {
            lred[0][p][0][lane] = make_float4(acc[0][p].x, acc[1][p].x, acc[2][p].x, acc[3][p].x);
            lred[0][p][1][lane] = make_float4(acc[0][p].y, acc[1][p].y, acc[2][p].y, acc[3][p].y);
        }
    }
    __syncthreads();
    if (w == 0) {
#pragma unroll
        for (int p = 0; p < NP; ++p) {
            const float4 a = lred[0][p][0][lane];
            const float4 b = lred[0][p][1][lane];
            acc[0][p] += (f2){a.x, b.x};
            acc[1][p] += (f2){a.y, b.y};
            acc[2][p] += (f2){a.z, b.z};
            acc[3][p] += (f2){a.w, b.w};
            const size_t base = (size_t)pg * (HW * HW) + (size_t)(tile * NP + p) * HW;
            part[base + lane]      = make_float4(acc[0][p].x, acc[1][p].x, acc[2][p].x, acc[3][p].x);
            part[base + 64 + lane] = make_float4(acc[0][p].y, acc[1][p].y, acc[2][p].y, acc[3][p].y);
        }
    }
}

// out[pix] = sum of the NPART partials
__global__ __launch_bounds__(256) void splat_combine(
    const float4* __restrict__ part, float4* __restrict__ out)
{
    const int i = blockIdx.x * 256 + threadIdx.x;
    float4 s = part[i];
#pragma unroll
    for (int gg = 1; gg < NPART; ++gg) {
        const float4 v = part[(size_t)gg * (HW * HW) + i];
        s.x += v.x; s.y += v.y; s.z += v.z; s.w += v.w;
    }
    out[i] = s;
}

extern "C" void kernel_launch(void* const* d_in, const int* in_sizes, int n_in,
                              void* d_out, int out_size, void* d_ws, size_t ws_size,
                              hipStream_t stream) {
    const float* rho    = (const float*)d_in[0];
    const float* sigma  = (const float*)d_in[1];
    const float* coords = (const float*)d_in[2];
    const float* alpha  = (const float*)d_in[3];
    const float* colors = (const float*)d_in[4];
    const float* tm     = (const float*)d_in[5];

    const int n_splats = in_sizes[0];
    const int nsp_pad  = (n_splats + 511) & ~511;   // %512==0 (NGROUPS=128 ok)

    // workspace layout (256 B aligned):
    //   tab  : nsp_pad * 64 * float4   (qb/qc for both column halves)
    //   urec : nsp_pad * 5 * float     (SoA-blocked per group)
    //   part : NPART * 16384 * float4
    char* wsb = (char*)d_ws;
    float4* tab = (float4*)wsb;
    size_t off = ((size_t)nsp_pad * 64 * sizeof(float4) + 255) & ~(size_t)255;
    float* urec = (float*)(wsb + off);
    off = (off + (size_t)nsp_pad * NUNI * sizeof(float) + 255) & ~(size_t)255;
    float4* part = (float4*)(wsb + off);

    splat_setup_max<<<nsp_pad / 4, 256, 0, stream>>>(
        rho, sigma, coords, alpha, colors, tm, tab, urec, n_splats, nsp_pad);
    splat_accum<<<NTILE * NPART, 512, 0, stream>>>(tab, urec, part, nsp_pad);
    splat_combine<<<(HW * HW) / 256, 256, 0, stream>>>(part, (float4*)d_out);
}